// Round 1
// baseline (606.737 us; speedup 1.0000x reference)
//
#include <hip/hip_runtime.h>
#include <hip/hip_bf16.h>

// DeepseekV4 shared expert: int8 dynamic-quant SwiGLU MLP.
// T=8192 tokens, H=4096 hidden, I=2048 intermediate (derived from in_sizes).
// Pipeline: wconv x3 -> quant_x -> gemm1(gate+up fused, silu, clip, bf16)
//           -> quant_inter -> gemm2 -> out fp32.

typedef __attribute__((ext_vector_type(4))) int i32x4;

__device__ __forceinline__ void async16(void* lds, const void* g) {
  __builtin_amdgcn_global_load_lds(
      (const __attribute__((address_space(1))) void*)g,
      (__attribute__((address_space(3))) void*)lds, 16, 0, 0);
}

__device__ __forceinline__ i32x4 mfma_i8(i32x4 a, i32x4 b, i32x4 c) {
  return __builtin_amdgcn_mfma_i32_16x16x64_i8(a, b, c, 0, 0, 0);
}

// fp32 -> bf16 round-to-nearest-even, back to fp32
__device__ __forceinline__ float bf16_rne_f(float f) {
  unsigned u = __float_as_uint(f);
  u += 0x7fffu + ((u >> 16) & 1u);
  return __uint_as_float(u & 0xffff0000u);
}

__device__ __forceinline__ unsigned short bf16_bits(float f) {
  unsigned u = __float_as_uint(f);
  u += 0x7fffu + ((u >> 16) & 1u);
  return (unsigned short)(u >> 16);
}

__device__ __forceinline__ float bf16_to_f(unsigned short h) {
  return __uint_as_float(((unsigned)h) << 16);
}

// ---------------- weight fp32 (int8-valued) -> int8 ----------------
__global__ void wconv_kernel(const float* __restrict__ w,
                             signed char* __restrict__ wq, int n) {
  int i = (blockIdx.x * 256 + threadIdx.x) * 4;
  if (i >= n) return;
  float4 f = *(const float4*)(w + i);
  signed char c[4] __attribute__((aligned(4)));
  c[0] = (signed char)(int)rintf(f.x);
  c[1] = (signed char)(int)rintf(f.y);
  c[2] = (signed char)(int)rintf(f.z);
  c[3] = (signed char)(int)rintf(f.w);
  *(int*)(wq + i) = *(const int*)c;
}

// ---------------- per-token quant of x (both gate & up smoothing) ----------------
__global__ __launch_bounds__(256) void quant_x_kernel(
    const float* __restrict__ x, const float* __restrict__ invg,
    const float* __restrict__ invu, signed char* __restrict__ qg,
    signed char* __restrict__ qu, float* __restrict__ sg,
    float* __restrict__ su, int H) {
  const int t = blockIdx.x, tid = threadIdx.x;
  const float* xr = x + (size_t)t * H;
  const int c0 = tid * 16;  // 256 threads * 16 = 4096 = H
  float xg[16], xu[16];
  float mg = 0.f, mu = 0.f;
#pragma unroll
  for (int v = 0; v < 4; ++v) {
    float4 f = *(const float4*)(xr + c0 + v * 4);
    float4 ig = *(const float4*)(invg + c0 + v * 4);
    float4 iu = *(const float4*)(invu + c0 + v * 4);
    float b0 = bf16_rne_f(f.x), b1 = bf16_rne_f(f.y);
    float b2 = bf16_rne_f(f.z), b3 = bf16_rne_f(f.w);
    xg[v * 4 + 0] = b0 * ig.x; xg[v * 4 + 1] = b1 * ig.y;
    xg[v * 4 + 2] = b2 * ig.z; xg[v * 4 + 3] = b3 * ig.w;
    xu[v * 4 + 0] = b0 * iu.x; xu[v * 4 + 1] = b1 * iu.y;
    xu[v * 4 + 2] = b2 * iu.z; xu[v * 4 + 3] = b3 * iu.w;
#pragma unroll
    for (int j = 0; j < 4; ++j) {
      mg = fmaxf(mg, fabsf(xg[v * 4 + j]));
      mu = fmaxf(mu, fabsf(xu[v * 4 + j]));
    }
  }
#pragma unroll
  for (int off = 32; off > 0; off >>= 1) {
    mg = fmaxf(mg, __shfl_xor(mg, off));
    mu = fmaxf(mu, __shfl_xor(mu, off));
  }
  __shared__ float smg[4], smu[4];
  if ((tid & 63) == 0) { smg[tid >> 6] = mg; smu[tid >> 6] = mu; }
  __syncthreads();
  mg = fmaxf(fmaxf(smg[0], smg[1]), fmaxf(smg[2], smg[3]));
  mu = fmaxf(fmaxf(smu[0], smu[1]), fmaxf(smu[2], smu[3]));
  const float scg = fmaxf(mg / 127.0f, 1e-8f);  // true division, matches np
  const float scu = fmaxf(mu / 127.0f, 1e-8f);
  signed char og[16] __attribute__((aligned(16)));
  signed char ou[16] __attribute__((aligned(16)));
#pragma unroll
  for (int j = 0; j < 16; ++j) {
    og[j] = (signed char)(int)fminf(fmaxf(rintf(xg[j] / scg), -127.f), 127.f);
    ou[j] = (signed char)(int)fminf(fmaxf(rintf(xu[j] / scu), -127.f), 127.f);
  }
  *(i32x4*)(qg + (size_t)t * H + c0) = *(const i32x4*)og;
  *(i32x4*)(qu + (size_t)t * H + c0) = *(const i32x4*)ou;
  if (tid == 0) { sg[t] = scg; su[t] = scu; }
}

// ---------------- fused gate+up GEMM + SwiGLU -> inter (bf16 bits) ----------------
// C[T,I] tiles of 128x128; A=[T,H] int8 row-major, W=[I,H] int8 row-major (B^T form).
__global__ __launch_bounds__(256, 2) void gemm1_kernel(
    const signed char* __restrict__ qg, const signed char* __restrict__ qu,
    const float* __restrict__ sg, const float* __restrict__ su,
    const signed char* __restrict__ wg, const signed char* __restrict__ wu,
    const float* __restrict__ swg, const float* __restrict__ swu,
    unsigned short* __restrict__ inter, int H, int I) {
  __shared__ signed char Ag[128 * 64] __attribute__((aligned(16)));
  __shared__ signed char Au[128 * 64] __attribute__((aligned(16)));
  __shared__ signed char Bg[128 * 64] __attribute__((aligned(16)));
  __shared__ signed char Bu[128 * 64] __attribute__((aligned(16)));
  const int tid = threadIdx.x;
  const int lane = tid & 63, wave = tid >> 6;
  const int row0 = blockIdx.x * 128, col0 = blockIdx.y * 128;
  const int wm = (wave & 1) * 64, wn = (wave >> 1) * 64;
  const int mrow = lane & 15, quad = lane >> 4;

  i32x4 accG[4][4], accU[4][4];
#pragma unroll
  for (int i = 0; i < 4; ++i)
#pragma unroll
    for (int j = 0; j < 4; ++j) {
      accG[i][j] = i32x4{0, 0, 0, 0};
      accU[i][j] = i32x4{0, 0, 0, 0};
    }

  for (int kk = 0; kk < H; kk += 64) {
    __syncthreads();
#pragma unroll
    for (int p = 0; p < 2; ++p) {
      const int g = p * 256 + tid;
      const int r = g >> 2, cb = (g & 3) << 4;
      const size_t ga = (size_t)(row0 + r) * H + kk + cb;
      const size_t gb = (size_t)(col0 + r) * H + kk + cb;
      async16(&Ag[g * 16], qg + ga);
      async16(&Au[g * 16], qu + ga);
      async16(&Bg[g * 16], wg + gb);
      async16(&Bu[g * 16], wu + gb);
    }
    __syncthreads();
    i32x4 aG[4], aU[4], bG[4], bU[4];
#pragma unroll
    for (int i = 0; i < 4; ++i) {
      aG[i] = *(const i32x4*)&Ag[(wm + i * 16 + mrow) * 64 + quad * 16];
      aU[i] = *(const i32x4*)&Au[(wm + i * 16 + mrow) * 64 + quad * 16];
      bG[i] = *(const i32x4*)&Bg[(wn + i * 16 + mrow) * 64 + quad * 16];
      bU[i] = *(const i32x4*)&Bu[(wn + i * 16 + mrow) * 64 + quad * 16];
    }
#pragma unroll
    for (int i = 0; i < 4; ++i)
#pragma unroll
      for (int j = 0; j < 4; ++j) {
        accG[i][j] = mfma_i8(aG[i], bG[j], accG[i][j]);
        accU[i][j] = mfma_i8(aU[i], bU[j], accU[i][j]);
      }
  }

  // epilogue: dequant, silu(g)*u, clip +-10, bf16 RNE, store
  float swgc[4], swuc[4];
#pragma unroll
  for (int j = 0; j < 4; ++j) {
    const int c = col0 + wn + j * 16 + mrow;
    swgc[j] = swg[c];
    swuc[j] = swu[c];
  }
#pragma unroll
  for (int i = 0; i < 4; ++i) {
#pragma unroll
    for (int r = 0; r < 4; ++r) {
      const int row = row0 + wm + i * 16 + quad * 4 + r;
      const float sgr = sg[row], sur = su[row];
#pragma unroll
      for (int j = 0; j < 4; ++j) {
        const int c = col0 + wn + j * 16 + mrow;
        const float g = (float)accG[i][j][r] * sgr * swgc[j];
        const float u = (float)accU[i][j][r] * sur * swuc[j];
        const float sig = 1.f / (1.f + expf(-g));
        float v = (g * sig) * u;
        v = fminf(fmaxf(v, -10.f), 10.f);
        inter[(size_t)row * I + c] = bf16_bits(v);
      }
    }
  }
}

// ---------------- per-token quant of inter ----------------
__global__ __launch_bounds__(256) void quant_i_kernel(
    const unsigned short* __restrict__ inter, const float* __restrict__ invi,
    signed char* __restrict__ qi, float* __restrict__ si, int I) {
  const int t = blockIdx.x, tid = threadIdx.x;
  const unsigned short* ir = inter + (size_t)t * I;
  const int c0 = tid * 8;  // 256*8 = 2048 = I
  uint4 pk = *(const uint4*)(ir + c0);
  float4 i0 = *(const float4*)(invi + c0);
  float4 i1 = *(const float4*)(invi + c0 + 4);
  float xs[8];
  xs[0] = bf16_to_f(pk.x & 0xffffu) * i0.x;
  xs[1] = bf16_to_f(pk.x >> 16) * i0.y;
  xs[2] = bf16_to_f(pk.y & 0xffffu) * i0.z;
  xs[3] = bf16_to_f(pk.y >> 16) * i0.w;
  xs[4] = bf16_to_f(pk.z & 0xffffu) * i1.x;
  xs[5] = bf16_to_f(pk.z >> 16) * i1.y;
  xs[6] = bf16_to_f(pk.w & 0xffffu) * i1.z;
  xs[7] = bf16_to_f(pk.w >> 16) * i1.w;
  float m = 0.f;
#pragma unroll
  for (int j = 0; j < 8; ++j) m = fmaxf(m, fabsf(xs[j]));
#pragma unroll
  for (int off = 32; off > 0; off >>= 1) m = fmaxf(m, __shfl_xor(m, off));
  __shared__ float sm[4];
  if ((tid & 63) == 0) sm[tid >> 6] = m;
  __syncthreads();
  m = fmaxf(fmaxf(sm[0], sm[1]), fmaxf(sm[2], sm[3]));
  const float s = fmaxf(m / 127.0f, 1e-8f);
  signed char o[8] __attribute__((aligned(8)));
#pragma unroll
  for (int j = 0; j < 8; ++j)
    o[j] = (signed char)(int)fminf(fmaxf(rintf(xs[j] / s), -127.f), 127.f);
  *(unsigned long long*)(qi + (size_t)t * I + c0) = *(const unsigned long long*)o;
  if (tid == 0) si[t] = s;
}

// ---------------- down GEMM -> out fp32 ----------------
__global__ __launch_bounds__(256, 2) void gemm2_kernel(
    const signed char* __restrict__ qi, const float* __restrict__ si,
    const signed char* __restrict__ wd, const float* __restrict__ swd,
    float* __restrict__ out, int H, int I) {
  __shared__ signed char As[128 * 64] __attribute__((aligned(16)));
  __shared__ signed char Bs[128 * 64] __attribute__((aligned(16)));
  const int tid = threadIdx.x;
  const int lane = tid & 63, wave = tid >> 6;
  const int row0 = blockIdx.x * 128, col0 = blockIdx.y * 128;
  const int wm = (wave & 1) * 64, wn = (wave >> 1) * 64;
  const int mrow = lane & 15, quad = lane >> 4;

  i32x4 acc[4][4];
#pragma unroll
  for (int i = 0; i < 4; ++i)
#pragma unroll
    for (int j = 0; j < 4; ++j) acc[i][j] = i32x4{0, 0, 0, 0};

  for (int kk = 0; kk < I; kk += 64) {
    __syncthreads();
#pragma unroll
    for (int p = 0; p < 2; ++p) {
      const int g = p * 256 + tid;
      const int r = g >> 2, cb = (g & 3) << 4;
      async16(&As[g * 16], qi + (size_t)(row0 + r) * I + kk + cb);
      async16(&Bs[g * 16], wd + (size_t)(col0 + r) * I + kk + cb);
    }
    __syncthreads();
    i32x4 a[4], b[4];
#pragma unroll
    for (int i = 0; i < 4; ++i) {
      a[i] = *(const i32x4*)&As[(wm + i * 16 + mrow) * 64 + quad * 16];
      b[i] = *(const i32x4*)&Bs[(wn + i * 16 + mrow) * 64 + quad * 16];
    }
#pragma unroll
    for (int i = 0; i < 4; ++i)
#pragma unroll
      for (int j = 0; j < 4; ++j) acc[i][j] = mfma_i8(a[i], b[j], acc[i][j]);
  }

  float swc[4];
#pragma unroll
  for (int j = 0; j < 4; ++j) swc[j] = swd[col0 + wn + j * 16 + mrow];
#pragma unroll
  for (int i = 0; i < 4; ++i) {
#pragma unroll
    for (int r = 0; r < 4; ++r) {
      const int row = row0 + wm + i * 16 + quad * 4 + r;
      const float sir = si[row];
#pragma unroll
      for (int j = 0; j < 4; ++j) {
        const int c = col0 + wn + j * 16 + mrow;
        out[(size_t)row * H + c] = (float)acc[i][j][r] * sir * swc[j];
      }
    }
  }
}

extern "C" void kernel_launch(void* const* d_in, const int* in_sizes, int n_in,
                              void* d_out, int out_size, void* d_ws,
                              size_t ws_size, hipStream_t stream) {
  const float* x = (const float*)d_in[0];
  const float* w_gate = (const float*)d_in[1];
  const float* s_wgate = (const float*)d_in[2];
  const float* w_up = (const float*)d_in[3];
  const float* s_wup = (const float*)d_in[4];
  const float* w_down = (const float*)d_in[5];
  const float* s_wdown = (const float*)d_in[6];
  const float* inv_gate = (const float*)d_in[7];
  const float* inv_up = (const float*)d_in[8];
  const float* inv_inter = (const float*)d_in[9];
  float* out = (float*)d_out;

  const int H = in_sizes[6];          // 4096
  const int I = in_sizes[2];          // 2048
  const int T = in_sizes[0] / H;      // 8192

  char* ws = (char*)d_ws;
  size_t off = 0;
  signed char* wqg = (signed char*)(ws + off); off += (size_t)I * H;
  signed char* wqu = (signed char*)(ws + off); off += (size_t)I * H;
  signed char* wqd = (signed char*)(ws + off); off += (size_t)H * I;
  signed char* qg  = (signed char*)(ws + off); off += (size_t)T * H;
  signed char* qu  = (signed char*)(ws + off); off += (size_t)T * H;
  unsigned short* inter = (unsigned short*)(ws + off); off += (size_t)T * I * 2;
  float* sg = (float*)(ws + off); off += (size_t)T * 4;
  float* su = (float*)(ws + off); off += (size_t)T * 4;
  float* si = (float*)(ws + off); off += (size_t)T * 4;
  signed char* qi = qg;  // qg is dead after gemm1; reuse for qi

  const int nW = I * H;
  wconv_kernel<<<nW / 1024, 256, 0, stream>>>(w_gate, wqg, nW);
  wconv_kernel<<<nW / 1024, 256, 0, stream>>>(w_up, wqu, nW);
  wconv_kernel<<<nW / 1024, 256, 0, stream>>>(w_down, wqd, nW);

  quant_x_kernel<<<T, 256, 0, stream>>>(x, inv_gate, inv_up, qg, qu, sg, su, H);

  dim3 g1(T / 128, I / 128);
  gemm1_kernel<<<g1, 256, 0, stream>>>(qg, qu, sg, su, wqg, wqu, s_wgate,
                                       s_wup, inter, H, I);

  quant_i_kernel<<<T, 256, 0, stream>>>(inter, inv_inter, qi, si, I);

  dim3 g2(T / 128, H / 128);
  gemm2_kernel<<<g2, 256, 0, stream>>>(qi, si, wqd, s_wdown, out, H, I);
}